// Round 1
// baseline (108.774 us; speedup 1.0000x reference)
//
#include <hip/hip_runtime.h>
#include <hip/hip_bf16.h>

// TaskSpecificLinear: out[n,:] = x[n,:] @ W[task_ids[n],:,:]
// N=2048 samples, IN=256, OUT=256, T=128 tasks, all fp32 (ids int).
//
// Strategy (R1): group-by-task so each W[t] (256 KB) is read exactly once
// from global. Grid = (T, 2 output halves) = 256 blocks of 256 threads
// (1 block/CU). Each block scans task_ids, builds its sample list in LDS,
// then processes chunks of 16 samples with x staged transposed in LDS
// (stride 20 floats -> aligned ds_read_b128 broadcast reads).
// Inner loop per i: 1 dwordx2 W load + 1 b128 LDS read + 8 v_fmac_f32.

#define NSAMP 2048
#define INSZ  256
#define OUTSZ 256
#define NTASK 128
#define CHUNK 16
#define XT_STRIDE 20   // 16 samples + pad; 80 B rows keep b128 reads aligned

__global__ __launch_bounds__(256, 1)
void TaskSpecificLinear_24910810316924_kernel(
    const float* __restrict__ X,
    const int*   __restrict__ ids32,   // may actually be int64 layout; detected
    const float* __restrict__ W,
    float*       __restrict__ out)
{
    __shared__ int   list[NSAMP];
    __shared__ int   s_cnt;
    __shared__ int   s_odd_nonzero;
    __shared__ float xt[INSZ * XT_STRIDE];   // 20 KB

    const int tid  = threadIdx.x;
    const int t    = blockIdx.x;     // task id
    const int half = blockIdx.y;     // output half (0/1)

    if (tid == 0) { s_cnt = 0; s_odd_nonzero = 0; }
    __syncthreads();

    // --- detect id layout: ids < 128, so if stored as int64 every odd
    // 32-bit word (high half) is 0. If stored as int32, odd words are
    // random ids — P(all zero) ~ (1/128)^1024 ~ 0.
    // Scan only odd indices < 2048: in-bounds for both layouts.
    {
        int any = 0;
        for (int j = 1 + 2 * tid; j < NSAMP; j += 2 * 256)
            any |= ids32[j];
        if (any) s_odd_nonzero = 1;   // benign race: all writers store 1
    }
    __syncthreads();
    const bool is64 = (s_odd_nonzero == 0);

    // --- build sample list for this task (order irrelevant: each sample
    // writes its own output row; only this block consumes this list)
    for (int n = tid; n < NSAMP; n += 256) {
        int id = is64 ? ids32[2 * n] : ids32[n];
        if (id == t) {
            int p = atomicAdd(&s_cnt, 1);
            list[p] = n;
        }
    }
    __syncthreads();
    const int count = s_cnt;

    const int o_lane = tid & 63;     // wave lane -> output pair
    const int s_lane = tid >> 6;     // wave index -> sample group of 4
    const int o0 = half * 128 + o_lane * 2;
    const float* Wt = W + (size_t)t * INSZ * OUTSZ + o0;

    for (int c = 0; c < count; c += CHUNK) {
        const int sc = min(CHUNK, count - c);
        __syncthreads();   // previous chunk's readers done before restage
        // stage x transposed: xt[i][s] ; coalesced row reads (tid == i)
        for (int s = 0; s < sc; ++s) {
            int n = list[c + s];
            xt[tid * XT_STRIDE + s] = X[(size_t)n * INSZ + tid];
        }
        __syncthreads();

        float2 a0 = {0.f, 0.f}, a1 = {0.f, 0.f}, a2 = {0.f, 0.f}, a3 = {0.f, 0.f};
        const float* wp = Wt;
        #pragma unroll 4
        for (int i = 0; i < INSZ; ++i) {
            const float2 w  = *(const float2*)wp;                       // coalesced 512B/wave
            const float4 xs = *(const float4*)&xt[i * XT_STRIDE + s_lane * 4]; // wave-broadcast
            a0.x += xs.x * w.x; a0.y += xs.x * w.y;
            a1.x += xs.y * w.x; a1.y += xs.y * w.y;
            a2.x += xs.z * w.x; a2.y += xs.z * w.y;
            a3.x += xs.w * w.x; a3.y += xs.w * w.y;
            wp += OUTSZ;
        }

        const int base = c + s_lane * 4;
        float2 acc[4] = {a0, a1, a2, a3};
        #pragma unroll
        for (int js = 0; js < 4; ++js) {
            int idx = base + js;
            if (idx < count) {
                int n = list[idx];
                *(float2*)&out[(size_t)n * OUTSZ + o0] = acc[js];
            }
        }
    }
}

extern "C" void kernel_launch(void* const* d_in, const int* in_sizes, int n_in,
                              void* d_out, int out_size, void* d_ws, size_t ws_size,
                              hipStream_t stream) {
    const float* X   = (const float*)d_in[0];
    const int*   ids = (const int*)d_in[1];
    const float* W   = (const float*)d_in[2];
    float*       out = (float*)d_out;

    dim3 grid(NTASK, 2, 1);
    dim3 block(256, 1, 1);
    TaskSpecificLinear_24910810316924_kernel<<<grid, block, 0, stream>>>(X, ids, W, out);
}